// Round 5
// baseline (15243.005 us; speedup 1.0000x reference)
//
#include <hip/hip_runtime.h>

#define N_USERS_C 100000
#define N_OUTFITS_C 100000
#define N_NODES_C 200000
#define EMBED_C 128
#define LAYERS_C 3
#define NEG_SLOPE_C 0.01f
#define EPS_C 1e-12f

#define NCOARSE 25
#define CSHIFT 13          // 8192 rows per coarse bucket
#define CBCAP 270336       // mean 262144 + 16 sigma
#define NFINE 1600         // 64 fine per coarse, 128 rows each
#define FB_ROWS 128
#define FCAP 4736          // mean 4096 + 10 sigma
#define NFB_USED 1563      // ceil(200000/128)

typedef float f32x4 __attribute__((ext_vector_type(4)));
typedef short s16x8 __attribute__((ext_vector_type(8)));
typedef __bf16 bf16x8 __attribute__((ext_vector_type(8)));

// ---- MFMA shim: works whether the builtin wants short8 or bf16x8 ----
template <typename T>
__device__ inline auto mfma_bf16_(T a, T b, f32x4 c, int)
    -> decltype(__builtin_amdgcn_mfma_f32_16x16x32_bf16(a, b, c, 0, 0, 0)) {
  return __builtin_amdgcn_mfma_f32_16x16x32_bf16(a, b, c, 0, 0, 0);
}
template <typename T>
__device__ inline f32x4 mfma_bf16_(T a, T b, f32x4 c, long) {
  union U { T s; bf16x8 b; };
  U ua; ua.s = a;
  U ub; ub.s = b;
  return __builtin_amdgcn_mfma_f32_16x16x32_bf16(ua.b, ub.b, c, 0, 0, 0);
}
__device__ inline f32x4 MFMA16(s16x8 a, s16x8 b, f32x4 c) {
  return mfma_bf16_(a, b, c, 0);
}

// ---- bf16 helpers (manual RNE) ----
__device__ inline unsigned short f2bf(float x) {
  unsigned u = __builtin_bit_cast(unsigned, x);
  u = (u + 0x7fffu + ((u >> 16) & 1u)) >> 16;
  return (unsigned short)u;
}
__device__ inline float bf2f(unsigned short h) {
  unsigned u = ((unsigned)h) << 16;
  return __builtin_bit_cast(float, u);
}
__device__ inline float bflo(unsigned u) {
  return __builtin_bit_cast(float, u << 16);
}
__device__ inline float bfhi(unsigned u) {
  return __builtin_bit_cast(float, u & 0xffff0000u);
}

// ---------------------------------------------------------------- init cursors
__global__ __launch_bounds__(256) void init_gcur(int* __restrict__ cg,
                                                 int* __restrict__ fg) {
  int t = blockIdx.x * 256 + threadIdx.x;
  if (t < NCOARSE) cg[t] = t * CBCAP;
  if (t < NFINE) fg[t] = t * FCAP;
}

// ---------------------------------------------------------------- init ego/out
__global__ __launch_bounds__(256) void init_ego_out(
    const float* __restrict__ user_emb, const int* __restrict__ u_id,
    const float* __restrict__ o_emb, unsigned short* __restrict__ ego_a,
    float* __restrict__ out) {
  int i4 = blockIdx.x * blockDim.x + threadIdx.x;
  if (i4 >= N_NODES_C * (EMBED_C / 4)) return;
  int r = i4 >> 5;
  int c4 = i4 & 31;
  float4 v;
  if (r < N_USERS_C) {
    int src = u_id[r];
    v = reinterpret_cast<const float4*>(user_emb)[(size_t)src * 32 + c4];
  } else {
    v = reinterpret_cast<const float4*>(o_emb)[(size_t)(r - N_USERS_C) * 32 + c4];
  }
  reinterpret_cast<float4*>(out)[i4] = v;
  float vv[4] = {v.x, v.y, v.z, v.w};
  ushort4 h;
  unsigned short* hp = (unsigned short*)&h;
#pragma unroll
  for (int j = 0; j < 4; ++j) hp[j] = f2bf(vv[j]);
  reinterpret_cast<ushort4*>(ego_a)[i4] = h;
}

// ---------------------------------------------------------------- A1: coarse partition
__global__ __launch_bounds__(256) void partition_edges(
    const int* __restrict__ erow, const int* __restrict__ ecol,
    const float* __restrict__ eval, int* __restrict__ cgcur,
    int2* __restrict__ cstage, int nnz) {
  __shared__ int2 scratch[2048];
  __shared__ unsigned char sbid[2048];
  __shared__ int hist[NCOARSE], lbase[NCOARSE], gbase[NCOARSE];
  int t = threadIdx.x;
  int base = blockIdx.x * 2048;
  if (base + 2048 > nnz) return;  // nnz divisible by 2048
  if (t < NCOARSE) hist[t] = 0;
  __syncthreads();
  int rowv[8], colv[8], bb[8], rk[8], vv[8];
#pragma unroll
  for (int r = 0; r < 8; ++r) {
    int e = base + t + r * 256;
    rowv[r] = erow[e];
    colv[r] = ecol[e];
    vv[r] = __builtin_bit_cast(int, eval[e]);
  }
#pragma unroll
  for (int r = 0; r < 8; ++r) {
    bb[r] = rowv[r] >> CSHIFT;
    rk[r] = atomicAdd(&hist[bb[r]], 1);
  }
  __syncthreads();
  if (t < 64) {
    int v = (t < NCOARSE) ? hist[t] : 0;
    int s = v;
#pragma unroll
    for (int off = 1; off < 32; off <<= 1) {
      int n = __shfl_up(s, off);
      if (t >= off) s += n;
    }
    if (t < NCOARSE) lbase[t] = s - v;
  }
  __syncthreads();
  if (t < NCOARSE) gbase[t] = atomicAdd(&cgcur[t], hist[t]);
  __syncthreads();
#pragma unroll
  for (int r = 0; r < 8; ++r) {
    int slot = lbase[bb[r]] + rk[r];
    int2 p;
    p.x = (int)(((unsigned)(rowv[r] & ((1 << CSHIFT) - 1)) << 18) |
                (unsigned)colv[r]);
    p.y = vv[r];
    scratch[slot] = p;
    sbid[slot] = (unsigned char)bb[r];
  }
  __syncthreads();
#pragma unroll
  for (int q = 0; q < 8; ++q) {
    int i = t + q * 256;
    int b = sbid[i];
    cstage[(size_t)gbase[b] + (i - lbase[b])] = scratch[i];
  }
}

// ---------------------------------------------------------------- A2: refine 25 -> 1600
__global__ __launch_bounds__(256) void refine_buckets(
    const int2* __restrict__ cstage, const int* __restrict__ cgcur,
    int* __restrict__ fgcur, int2* __restrict__ fstage) {
  __shared__ int2 scratch[2048];
  __shared__ short sbid[2048];
  __shared__ int hist[64], lbase[64], gbase[64];
  int b = blockIdx.x >> 5;  // coarse bucket
  int j = blockIdx.x & 31;  // chunk
  int t = threadIdx.x;
  int cnt = cgcur[b] - b * CBCAP;
  int s0 = (int)(((long)cnt * j) >> 5);
  int s1 = (int)(((long)cnt * (j + 1)) >> 5);
  const int2* src = cstage + (size_t)b * CBCAP;
  int fb0 = b * 64;
  for (int t0 = s0; t0 < s1; t0 += 2048) {
    int tn = s1 - t0;
    if (tn > 2048) tn = 2048;
    if (t < 64) hist[t] = 0;
    __syncthreads();
    int2 p[8];
    int sub[8], rk[8];
#pragma unroll
    for (int r = 0; r < 8; ++r) {
      int i = t + r * 256;
      if (i < tn) {
        p[r] = src[t0 + i];
        sub[r] = (int)(((unsigned)p[r].x >> 25) & 63);
        rk[r] = atomicAdd(&hist[sub[r]], 1);
      }
    }
    __syncthreads();
    if (t < 64) {
      int v = hist[t];
      int s = v;
#pragma unroll
      for (int off = 1; off < 64; off <<= 1) {
        int n = __shfl_up(s, off);
        if (t >= off) s += n;
      }
      lbase[t] = s - v;
    }
    __syncthreads();
    if (t < 64) gbase[t] = atomicAdd(&fgcur[fb0 + t], hist[t]);
    __syncthreads();
#pragma unroll
    for (int r = 0; r < 8; ++r) {
      int i = t + r * 256;
      if (i < tn) {
        int slot = lbase[sub[r]] + rk[r];
        int2 q;
        q.x = p[r].x & 0x1FFFFFF;  // keep col(18) + rowlocal7 (bits 18..24)
        q.y = p[r].y;
        scratch[slot] = q;
        sbid[slot] = (short)sub[r];
      }
    }
    __syncthreads();
    for (int i = t; i < tn; i += 256) {
      int bs = sbid[i];
      fstage[(size_t)gbase[bs] + (i - lbase[bs])] = scratch[i];
    }
    __syncthreads();
  }
}

// ---------------------------------------------------------------- W prep
__global__ __launch_bounds__(256) void prep_w(
    const float* __restrict__ fc1_w, const float* __restrict__ fc2_w,
    unsigned short* __restrict__ whi, unsigned short* __restrict__ wlo) {
  int idx = blockIdx.x * 256 + threadIdx.x;
  if (idx >= LAYERS_C * 128 * 256) return;
  int k = idx & 255;
  int j = (idx >> 8) & 127;
  int l = idx >> 15;
  float v = (k < 128) ? fc1_w[((size_t)l * 128 + j) * 128 + k]
                      : fc2_w[((size_t)l * 128 + j) * 128 + (k - 128)];
  unsigned short h = f2bf(v);
  whi[idx] = h;
  wlo[idx] = f2bf(v - bf2f(h));
}

// ---------------------------------------------------------------- fused layer
// Per fine bucket (128 rows): side = A@ego in LDS (f32 atomics, swizzled),
// then Y = [side|ego*side] @ [W1|W2]^T via split-bf16 MFMA, leaky, norm, out.
__global__ __launch_bounds__(1024, 4) void fused_layer(
    const int2* __restrict__ fstage, const int* __restrict__ fgcur,
    const unsigned short* __restrict__ ego_old,
    unsigned short* __restrict__ ego_new, const unsigned short* __restrict__ whi,
    const unsigned short* __restrict__ wlo, const float* __restrict__ b1,
    const float* __restrict__ b2, float* __restrict__ out) {
  __shared__ float acc_s[128 * 128];  // 64 KB; logical (row,col) at word
                                      // row*128 + (col ^ ((row&7)<<2))
  int t = threadIdx.x;
  int lane = t & 63;
  int w = t >> 6;  // 0..15
  int fb = blockIdx.x;
  int rbase = fb * FB_ROWS;

  // ---- phase 0: zero acc
#pragma unroll
  for (int i = 0; i < 16; ++i) acc_s[i * 1024 + t] = 0.f;
  __syncthreads();

  // ---- phase 1: edge accumulation (gather bf16 ego, LDS f32 atomic add)
  {
    int s = fb * FCAP;
    int e = fgcur[fb];
    const unsigned* eg = (const unsigned*)ego_old;
    for (int base = s + w * 64; base < e; base += 1024) {
      int n = e - base;
      if (n > 64) n = 64;
      int c = 0, vb = 0, rl = 0;
      if (lane < n) {
        int2 p = fstage[base + lane];
        c = p.x & 0x3FFFF;
        rl = (int)(((unsigned)p.x >> 18) & 127);
        vb = p.y;
      }
      int tt = 0;
      for (; tt + 8 <= n; tt += 8) {
        unsigned u[8];
        float vt[8];
        int rr[8];
#pragma unroll
        for (int q = 0; q < 8; ++q) {
          int ct = __shfl(c, tt + q);
          vt[q] = __builtin_bit_cast(float, __shfl(vb, tt + q));
          rr[q] = __shfl(rl, tt + q);
          u[q] = eg[(size_t)ct * 64 + lane];
        }
#pragma unroll
        for (int q = 0; q < 8; ++q) {
          int word = rr[q] * 128 + ((lane * 2) ^ ((rr[q] & 7) << 2));
          atomicAdd(&acc_s[word], vt[q] * bflo(u[q]));
          atomicAdd(&acc_s[word + 1], vt[q] * bfhi(u[q]));
        }
      }
      for (; tt < n; ++tt) {
        int ct = __shfl(c, tt);
        float vtt = __builtin_bit_cast(float, __shfl(vb, tt));
        int rt = __shfl(rl, tt);
        unsigned uu = eg[(size_t)ct * 64 + lane];
        int word = rt * 128 + ((lane * 2) ^ ((rt & 7) << 2));
        atomicAdd(&acc_s[word], vtt * bflo(uu));
        atomicAdd(&acc_s[word + 1], vtt * bfhi(uu));
      }
    }
  }
  __syncthreads();

  // ---- phase 2: dense MFMA
  int l15 = lane & 15;
  int lg = lane >> 4;
  int g = w >> 2;   // row tile 0..3 (32 rows each)
  int wq = w & 3;   // col quarter
  float bias[2];
#pragma unroll
  for (int ntl = 0; ntl < 2; ++ntl) {
    int col = (wq * 2 + ntl) * 16 + l15;
    bias[ntl] = b1[col] + b2[col];
  }
  f32x4 zero = {0.f, 0.f, 0.f, 0.f};
  f32x4 acc[2][2] = {{zero, zero}, {zero, zero}};
#pragma unroll
  for (int kt = 0; kt < 4; ++kt) {
    s16x8 shi[2], slo[2], phi[2], plo[2];
#pragma unroll
    for (int mt = 0; mt < 2; ++mt) {
      int row = g * 32 + mt * 16 + l15;
      int swzw = (row & 7) << 2;  // word-level XOR (bits 2..4)
      int kw = kt * 32 + lg * 8;  // word index of k0 within row
      f32x4 sa = *(const f32x4*)&acc_s[row * 128 + (kw ^ swzw)];
      f32x4 sb = *(const f32x4*)&acc_s[row * 128 + ((kw + 4) ^ swzw)];
      int grow = rbase + row;
      if (grow >= N_NODES_C) grow = N_NODES_C - 1;
      int4 ev = reinterpret_cast<const int4*>(ego_old)[(size_t)grow * 16 +
                                                       kt * 4 + lg];
      const unsigned* evu = (const unsigned*)&ev;
      float sv[8] = {sa.x, sa.y, sa.z, sa.w, sb.x, sb.y, sb.z, sb.w};
      union {
        s16x8 v;
        unsigned short a[8];
      } uh, ul, vh, vl;
#pragma unroll
      for (int k2 = 0; k2 < 4; ++k2) {
        float e0 = bflo(evu[k2]);
        float e1 = bfhi(evu[k2]);
        float s0 = sv[k2 * 2], s1 = sv[k2 * 2 + 1];
        unsigned short h0 = f2bf(s0), h1 = f2bf(s1);
        uh.a[k2 * 2] = h0;
        uh.a[k2 * 2 + 1] = h1;
        ul.a[k2 * 2] = f2bf(s0 - bf2f(h0));
        ul.a[k2 * 2 + 1] = f2bf(s1 - bf2f(h1));
        float p0 = s0 * e0, p1 = s1 * e1;
        unsigned short g0 = f2bf(p0), g1 = f2bf(p1);
        vh.a[k2 * 2] = g0;
        vh.a[k2 * 2 + 1] = g1;
        vl.a[k2 * 2] = f2bf(p0 - bf2f(g0));
        vl.a[k2 * 2 + 1] = f2bf(p1 - bf2f(g1));
      }
      shi[mt] = uh.v;
      slo[mt] = ul.v;
      phi[mt] = vh.v;
      plo[mt] = vl.v;
    }
    s16x8 w1h[2], w1l[2], w2h[2], w2l[2];
#pragma unroll
    for (int ntl = 0; ntl < 2; ++ntl) {
      int jj = (wq * 2 + ntl) * 16 + l15;
      size_t wo = (size_t)jj * 256 + kt * 32 + lg * 8;
      w1h[ntl] = *(const s16x8*)(whi + wo);
      w1l[ntl] = *(const s16x8*)(wlo + wo);
      w2h[ntl] = *(const s16x8*)(whi + wo + 128);
      w2l[ntl] = *(const s16x8*)(wlo + wo + 128);
    }
#pragma unroll
    for (int mt = 0; mt < 2; ++mt)
#pragma unroll
      for (int ntl = 0; ntl < 2; ++ntl) {
        acc[mt][ntl] = MFMA16(shi[mt], w1h[ntl], acc[mt][ntl]);
        acc[mt][ntl] = MFMA16(shi[mt], w1l[ntl], acc[mt][ntl]);
        acc[mt][ntl] = MFMA16(slo[mt], w1h[ntl], acc[mt][ntl]);
        acc[mt][ntl] = MFMA16(phi[mt], w2h[ntl], acc[mt][ntl]);
        acc[mt][ntl] = MFMA16(phi[mt], w2l[ntl], acc[mt][ntl]);
        acc[mt][ntl] = MFMA16(plo[mt], w2h[ntl], acc[mt][ntl]);
      }
  }
  __syncthreads();  // done reading acc_s as side

  // ---- epilogue: Y = leaky(acc+bias) into acc_s (swizzled f32 tile)
#pragma unroll
  for (int mt = 0; mt < 2; ++mt)
#pragma unroll
    for (int ntl = 0; ntl < 2; ++ntl) {
      int col = (wq * 2 + ntl) * 16 + l15;
#pragma unroll
      for (int r = 0; r < 4; ++r) {
        int row = g * 32 + mt * 16 + lg * 4 + r;
        float a = acc[mt][ntl][r] + bias[ntl];
        float yv = (a >= 0.f) ? a : NEG_SLOPE_C * a;
        acc_s[row * 128 + (col ^ ((row & 7) << 2))] = yv;
      }
    }
  __syncthreads();

  // ---- store: row norm + ego_new (bf16) + out (fp32 +=)
#pragma unroll
  for (int i = 0; i < 4; ++i) {
    int f = i * 1024 + t;
    int row = f >> 5;
    int c4 = f & 31;
    f32x4 y = *(const f32x4*)&acc_s[row * 128 + ((c4 * 4) ^ ((row & 7) << 2))];
    float ss = y.x * y.x + y.y * y.y + y.z * y.z + y.w * y.w;
#pragma unroll
    for (int m = 1; m <= 16; m <<= 1) ss += __shfl_xor(ss, m);
    int grow = rbase + row;
    if (grow < N_NODES_C) {
      float scale = 1.0f / fmaxf(sqrtf(ss), EPS_C);
      size_t gidx = (size_t)grow * 32 + c4;
      float yy[4] = {y.x, y.y, y.z, y.w};
      ushort4 h;
      unsigned short* hp = (unsigned short*)&h;
#pragma unroll
      for (int jj = 0; jj < 4; ++jj) hp[jj] = f2bf(yy[jj]);
      reinterpret_cast<ushort4*>(ego_new)[gidx] = h;
      float4 o = reinterpret_cast<float4*>(out)[gidx];
      o.x += y.x * scale;
      o.y += y.y * scale;
      o.z += y.z * scale;
      o.w += y.w * scale;
      reinterpret_cast<float4*>(out)[gidx] = o;
    }
  }
}

// ---------------------------------------------------------------- launch
extern "C" void kernel_launch(void* const* d_in, const int* in_sizes, int n_in,
                              void* d_out, int out_size, void* d_ws,
                              size_t ws_size, hipStream_t stream) {
  const int* erow = (const int*)d_in[0];
  const int* ecol = (const int*)d_in[1];
  const float* eval = (const float*)d_in[2];
  const float* o_emb = (const float*)d_in[3];
  const int* u_id = (const int*)d_in[4];
  const float* user_emb = (const float*)d_in[5];
  const float* fc1_w = (const float*)d_in[6];
  const float* fc1_b = (const float*)d_in[7];
  const float* fc2_w = (const float*)d_in[8];
  const float* fc2_b = (const float*)d_in[9];
  float* out = (float*)d_out;
  int nnz = in_sizes[0];

  char* ws = (char*)d_ws;
  size_t off = 0;
  auto alloc = [&](size_t bytes) {
    void* p = ws + off;
    off += (bytes + 255) & ~(size_t)255;
    return p;
  };
  unsigned short* ego_a = (unsigned short*)alloc((size_t)N_NODES_C * EMBED_C * 2);
  unsigned short* ego_b = (unsigned short*)alloc((size_t)N_NODES_C * EMBED_C * 2);
  int2* cstage = (int2*)alloc((size_t)NCOARSE * CBCAP * 8);
  int2* fstage = (int2*)alloc((size_t)NFINE * FCAP * 8);
  int* cgcur = (int*)alloc(NCOARSE * 4);
  int* fgcur = (int*)alloc(NFINE * 4);
  unsigned short* whi = (unsigned short*)alloc((size_t)LAYERS_C * 128 * 256 * 2);
  unsigned short* wlo = (unsigned short*)alloc((size_t)LAYERS_C * 128 * 256 * 2);

  init_gcur<<<(NFINE + 255) / 256, 256, 0, stream>>>(cgcur, fgcur);
  init_ego_out<<<(N_NODES_C * 32 + 255) / 256, 256, 0, stream>>>(
      user_emb, u_id, o_emb, ego_a, out);
  partition_edges<<<nnz / 2048, 256, 0, stream>>>(erow, ecol, eval, cgcur,
                                                  cstage, nnz);
  refine_buckets<<<NCOARSE * 32, 256, 0, stream>>>(cstage, cgcur, fgcur,
                                                   fstage);
  prep_w<<<(LAYERS_C * 128 * 256 + 255) / 256, 256, 0, stream>>>(fc1_w, fc2_w,
                                                                 whi, wlo);
  for (int l = 0; l < LAYERS_C; ++l) {
    const unsigned short* eo = (l & 1) ? ego_b : ego_a;
    unsigned short* en = (l & 1) ? ego_a : ego_b;
    fused_layer<<<NFB_USED, 1024, 0, stream>>>(
        fstage, fgcur, eo, en, whi + (size_t)l * 32768,
        wlo + (size_t)l * 32768, fc1_b + l * EMBED_C, fc2_b + l * EMBED_C, out);
  }
}

// Round 6
// 1287.037 us; speedup vs baseline: 11.8435x; 11.8435x over previous
//
#include <hip/hip_runtime.h>

#define N_USERS_C 100000
#define N_OUTFITS_C 100000
#define N_NODES_C 200000
#define EMBED_C 128
#define LAYERS_C 3
#define NEG_SLOPE_C 0.01f
#define EPS_C 1e-12f

#define NCOARSE 25
#define CSHIFT 13          // 8192 rows per coarse bucket
#define CBCAP 270336       // mean 262144 + 16 sigma
#define NFINE 1600         // 64 fine per coarse, 128 rows each
#define FB_ROWS 128
#define FCAP 4736          // mean 4096 + 10 sigma
#define NFB_USED 1563      // ceil(200000/128)

typedef float f32x4 __attribute__((ext_vector_type(4)));
typedef short s16x8 __attribute__((ext_vector_type(8)));
typedef __bf16 bf16x8 __attribute__((ext_vector_type(8)));

// ---- MFMA shim: works whether the builtin wants short8 or bf16x8 ----
template <typename T>
__device__ inline auto mfma_bf16_(T a, T b, f32x4 c, int)
    -> decltype(__builtin_amdgcn_mfma_f32_16x16x32_bf16(a, b, c, 0, 0, 0)) {
  return __builtin_amdgcn_mfma_f32_16x16x32_bf16(a, b, c, 0, 0, 0);
}
template <typename T>
__device__ inline f32x4 mfma_bf16_(T a, T b, f32x4 c, long) {
  union U { T s; bf16x8 b; };
  U ua; ua.s = a;
  U ub; ub.s = b;
  return __builtin_amdgcn_mfma_f32_16x16x32_bf16(ua.b, ub.b, c, 0, 0, 0);
}
__device__ inline f32x4 MFMA16(s16x8 a, s16x8 b, f32x4 c) {
  return mfma_bf16_(a, b, c, 0);
}

// ---- bf16 helpers (manual RNE) ----
__device__ inline unsigned short f2bf(float x) {
  unsigned u = __builtin_bit_cast(unsigned, x);
  u = (u + 0x7fffu + ((u >> 16) & 1u)) >> 16;
  return (unsigned short)u;
}
__device__ inline float bf2f(unsigned short h) {
  unsigned u = ((unsigned)h) << 16;
  return __builtin_bit_cast(float, u);
}
__device__ inline float bflo(unsigned u) {
  return __builtin_bit_cast(float, u << 16);
}
__device__ inline float bfhi(unsigned u) {
  return __builtin_bit_cast(float, u & 0xffff0000u);
}

// ---------------------------------------------------------------- init cursors
__global__ __launch_bounds__(256) void init_gcur(int* __restrict__ cg,
                                                 int* __restrict__ fg) {
  int t = blockIdx.x * 256 + threadIdx.x;
  if (t < NCOARSE) cg[t] = t * CBCAP;
  if (t < NFINE) fg[t] = t * FCAP;
}

// ---------------------------------------------------------------- init ego/out
__global__ __launch_bounds__(256) void init_ego_out(
    const float* __restrict__ user_emb, const int* __restrict__ u_id,
    const float* __restrict__ o_emb, unsigned short* __restrict__ ego,
    float* __restrict__ out) {
  int i4 = blockIdx.x * blockDim.x + threadIdx.x;
  if (i4 >= N_NODES_C * (EMBED_C / 4)) return;
  int r = i4 >> 5;
  int c4 = i4 & 31;
  float4 v;
  if (r < N_USERS_C) {
    int src = u_id[r];
    v = reinterpret_cast<const float4*>(user_emb)[(size_t)src * 32 + c4];
  } else {
    v = reinterpret_cast<const float4*>(o_emb)[(size_t)(r - N_USERS_C) * 32 + c4];
  }
  reinterpret_cast<float4*>(out)[i4] = v;
  float vv[4] = {v.x, v.y, v.z, v.w};
  ushort4 h;
  unsigned short* hp = (unsigned short*)&h;
#pragma unroll
  for (int j = 0; j < 4; ++j) hp[j] = f2bf(vv[j]);
  reinterpret_cast<ushort4*>(ego)[i4] = h;
}

// ---------------------------------------------------------------- A1: coarse partition
__global__ __launch_bounds__(256) void partition_edges(
    const int* __restrict__ erow, const int* __restrict__ ecol,
    const float* __restrict__ eval, int* __restrict__ cgcur,
    int2* __restrict__ cstage, int nnz) {
  __shared__ int2 scratch[2048];
  __shared__ unsigned char sbid[2048];
  __shared__ int hist[NCOARSE], lbase[NCOARSE], gbase[NCOARSE];
  int t = threadIdx.x;
  int base = blockIdx.x * 2048;
  if (base + 2048 > nnz) return;  // nnz divisible by 2048
  if (t < NCOARSE) hist[t] = 0;
  __syncthreads();
  int rowv[8], colv[8], bb[8], rk[8], vv[8];
#pragma unroll
  for (int r = 0; r < 8; ++r) {
    int e = base + t + r * 256;
    rowv[r] = erow[e];
    colv[r] = ecol[e];
    vv[r] = __builtin_bit_cast(int, eval[e]);
  }
#pragma unroll
  for (int r = 0; r < 8; ++r) {
    bb[r] = rowv[r] >> CSHIFT;
    rk[r] = atomicAdd(&hist[bb[r]], 1);
  }
  __syncthreads();
  if (t < 64) {
    int v = (t < NCOARSE) ? hist[t] : 0;
    int s = v;
#pragma unroll
    for (int off = 1; off < 32; off <<= 1) {
      int n = __shfl_up(s, off);
      if (t >= off) s += n;
    }
    if (t < NCOARSE) lbase[t] = s - v;
  }
  __syncthreads();
  if (t < NCOARSE) gbase[t] = atomicAdd(&cgcur[t], hist[t]);
  __syncthreads();
#pragma unroll
  for (int r = 0; r < 8; ++r) {
    int slot = lbase[bb[r]] + rk[r];
    int2 p;
    p.x = (int)(((unsigned)(rowv[r] & ((1 << CSHIFT) - 1)) << 18) |
                (unsigned)colv[r]);
    p.y = vv[r];
    scratch[slot] = p;
    sbid[slot] = (unsigned char)bb[r];
  }
  __syncthreads();
#pragma unroll
  for (int q = 0; q < 8; ++q) {
    int i = t + q * 256;
    int b = sbid[i];
    cstage[(size_t)gbase[b] + (i - lbase[b])] = scratch[i];
  }
}

// ---------------------------------------------------------------- A2: refine 25 -> 1600
__global__ __launch_bounds__(256) void refine_buckets(
    const int2* __restrict__ cstage, const int* __restrict__ cgcur,
    int* __restrict__ fgcur, int2* __restrict__ fstage) {
  __shared__ int2 scratch[2048];
  __shared__ short sbid[2048];
  __shared__ int hist[64], lbase[64], gbase[64];
  int b = blockIdx.x >> 5;  // coarse bucket
  int j = blockIdx.x & 31;  // chunk
  int t = threadIdx.x;
  int cnt = cgcur[b] - b * CBCAP;
  int s0 = (int)(((long)cnt * j) >> 5);
  int s1 = (int)(((long)cnt * (j + 1)) >> 5);
  const int2* src = cstage + (size_t)b * CBCAP;
  int fb0 = b * 64;
  for (int t0 = s0; t0 < s1; t0 += 2048) {
    int tn = s1 - t0;
    if (tn > 2048) tn = 2048;
    if (t < 64) hist[t] = 0;
    __syncthreads();
    int2 p[8];
    int sub[8], rk[8];
#pragma unroll
    for (int r = 0; r < 8; ++r) {
      int i = t + r * 256;
      if (i < tn) {
        p[r] = src[t0 + i];
        sub[r] = (int)(((unsigned)p[r].x >> 25) & 63);
        rk[r] = atomicAdd(&hist[sub[r]], 1);
      }
    }
    __syncthreads();
    if (t < 64) {
      int v = hist[t];
      int s = v;
#pragma unroll
      for (int off = 1; off < 64; off <<= 1) {
        int n = __shfl_up(s, off);
        if (t >= off) s += n;
      }
      lbase[t] = s - v;
    }
    __syncthreads();
    if (t < 64) gbase[t] = atomicAdd(&fgcur[fb0 + t], hist[t]);
    __syncthreads();
#pragma unroll
    for (int r = 0; r < 8; ++r) {
      int i = t + r * 256;
      if (i < tn) {
        int slot = lbase[sub[r]] + rk[r];
        int2 q;
        q.x = p[r].x & 0x1FFFFFF;  // col(18) + rowlocal7 (bits 18..24)
        q.y = p[r].y;
        scratch[slot] = q;
        sbid[slot] = (short)sub[r];
      }
    }
    __syncthreads();
    for (int i = t; i < tn; i += 256) {
      int bs = sbid[i];
      fstage[(size_t)gbase[bs] + (i - lbase[bs])] = scratch[i];
    }
    __syncthreads();
  }
}

// ---------------------------------------------------------------- W prep
__global__ __launch_bounds__(256) void prep_w(
    const float* __restrict__ fc1_w, const float* __restrict__ fc2_w,
    unsigned short* __restrict__ whi, unsigned short* __restrict__ wlo) {
  int idx = blockIdx.x * 256 + threadIdx.x;
  if (idx >= LAYERS_C * 128 * 256) return;
  int k = idx & 255;
  int j = (idx >> 8) & 127;
  int l = idx >> 15;
  float v = (k < 128) ? fc1_w[((size_t)l * 128 + j) * 128 + k]
                      : fc2_w[((size_t)l * 128 + j) * 128 + (k - 128)];
  unsigned short h = f2bf(v);
  whi[idx] = h;
  wlo[idx] = f2bf(v - bf2f(h));
}

// ---------------------------------------------------------------- SpMM per fine bucket
// In-LDS counting sort (row-local 7b key) -> per-row register accumulation
// (one wave owns a whole 128-col row; edge metadata via uniform LDS reads).
__global__ __launch_bounds__(512, 8) void spmm_bucket(
    const int2* __restrict__ fstage, const int* __restrict__ fgcur,
    const unsigned* __restrict__ ego, float* __restrict__ side) {
  __shared__ int2 se[FCAP];     // 37888 B sorted edges
  __shared__ int sbase[128];
  __shared__ int scur[128];
  __shared__ int shist[128];
  int t = threadIdx.x;
  int fb = blockIdx.x;
  int cnt = fgcur[fb] - fb * FCAP;
  if (t < 128) shist[t] = 0;
  __syncthreads();
  const int2* src = fstage + (size_t)fb * FCAP;
  // pass 1: histogram
  for (int i = t; i < cnt; i += 512) {
    int rw = (int)(((unsigned)src[i].x >> 18) & 127);
    atomicAdd(&shist[rw], 1);
  }
  __syncthreads();
  // scan (wave 0, 2 elems/lane)
  if (t < 64) {
    int h0 = shist[2 * t], h1 = shist[2 * t + 1];
    int s = h0 + h1;
    int pref = s;
#pragma unroll
    for (int off = 1; off < 64; off <<= 1) {
      int n = __shfl_up(pref, off);
      if (t >= off) pref += n;
    }
    int ex = pref - s;
    sbase[2 * t] = ex;
    scur[2 * t] = ex;
    sbase[2 * t + 1] = ex + h0;
    scur[2 * t + 1] = ex + h0;
  }
  __syncthreads();
  // pass 2: place edges (order within row arbitrary)
  for (int i = t; i < cnt; i += 512) {
    int2 p = src[i];
    int rw = (int)(((unsigned)p.x >> 18) & 127);
    int pos = atomicAdd(&scur[rw], 1);
    int2 o;
    o.x = p.x & 0x3FFFF;
    o.y = p.y;
    se[pos] = o;
  }
  __syncthreads();
  // per-row gather + register accumulate (wave owns row; 2 bf16 cols/lane)
  int wave = t >> 6, lane = t & 63;
  int rbase = fb * FB_ROWS;
  for (int r = wave; r < FB_ROWS; r += 8) {
    int grow = rbase + r;
    if (grow >= N_NODES_C) break;
    int s = sbase[r];
    int n = scur[r] - s;
    float ax = 0.f, ay = 0.f;
    int tt = 0;
    for (; tt + 8 <= n; tt += 8) {
      unsigned u[8];
      float vt[8];
#pragma unroll
      for (int q = 0; q < 8; ++q) {
        int2 p = se[s + tt + q];  // uniform addr -> broadcast, conflict-free
        vt[q] = __builtin_bit_cast(float, p.y);
        u[q] = ego[(size_t)p.x * 64 + lane];
      }
#pragma unroll
      for (int q = 0; q < 8; ++q) {
        ax = fmaf(vt[q], bflo(u[q]), ax);
        ay = fmaf(vt[q], bfhi(u[q]), ay);
      }
    }
    for (; tt < n; ++tt) {
      int2 p = se[s + tt];
      float vv = __builtin_bit_cast(float, p.y);
      unsigned uu = ego[(size_t)p.x * 64 + lane];
      ax = fmaf(vv, bflo(uu), ax);
      ay = fmaf(vv, bfhi(uu), ay);
    }
    float2 o;
    o.x = ax;
    o.y = ay;
    reinterpret_cast<float2*>(side)[(size_t)grow * 64 + lane] = o;
  }
}

// ---------------------------------------------------------------- fused dense layer (MFMA, split-bf16)
// Y[32][128] = Z[32][256] @ Wcat^T, Z = [side | ego*side], ego bf16.
// ego' = leaky(Y + b); ego <- bf16(ego') in place; out += ego'/max(||row||,eps).
__global__ __launch_bounds__(256) void dense_mfma(
    const float* __restrict__ side, unsigned short* __restrict__ ego,
    const unsigned short* __restrict__ whi, const unsigned short* __restrict__ wlo,
    const float* __restrict__ b1, const float* __restrict__ b2,
    float* __restrict__ out) {
  __shared__ unsigned short A_hi[32 * 256];
  __shared__ unsigned short A_lo[32 * 256];
  int t = threadIdx.x;
  int lane = t & 63;
  int w = t >> 6;
  int l15 = lane & 15;
  int lg = lane >> 4;
  int nb = blockIdx.x * 32;

#pragma unroll
  for (int i = 0; i < 4; ++i) {
    int f = i * 256 + t;
    int row = f >> 5;
    int c4 = f & 31;
    size_t g = (size_t)(nb + row) * 32 + c4;
    float4 sv = reinterpret_cast<const float4*>(side)[g];
    ushort4 hv = reinterpret_cast<const ushort4*>(ego)[g];
    const unsigned short* hvp = (const unsigned short*)&hv;
    float s_[4] = {sv.x, sv.y, sv.z, sv.w};
    ushort4 sh, sl, ph, pl;
    unsigned short* shp = (unsigned short*)&sh;
    unsigned short* slp = (unsigned short*)&sl;
    unsigned short* php = (unsigned short*)&ph;
    unsigned short* plp = (unsigned short*)&pl;
#pragma unroll
    for (int j = 0; j < 4; ++j) {
      float x = s_[j];
      unsigned short h = f2bf(x);
      shp[j] = h;
      slp[j] = f2bf(x - bf2f(h));
      float p = x * bf2f(hvp[j]);
      unsigned short hp2 = f2bf(p);
      php[j] = hp2;
      plp[j] = f2bf(p - bf2f(hp2));
    }
    int swz = (row & 7) << 4;
    int base_s = (row * 512 + c4 * 8) ^ swz;
    int base_p = (row * 512 + 256 + c4 * 8) ^ swz;
    *(ushort4*)((char*)A_hi + base_s) = sh;
    *(ushort4*)((char*)A_lo + base_s) = sl;
    *(ushort4*)((char*)A_hi + base_p) = ph;
    *(ushort4*)((char*)A_lo + base_p) = pl;
  }

  float bias[2];
#pragma unroll
  for (int ntl = 0; ntl < 2; ++ntl) {
    int col = (w * 2 + ntl) * 16 + l15;
    bias[ntl] = b1[col] + b2[col];
  }

  __syncthreads();

  f32x4 zero = {0.f, 0.f, 0.f, 0.f};
  f32x4 acc[2][2] = {{zero, zero}, {zero, zero}};
#pragma unroll
  for (int kt = 0; kt < 8; ++kt) {
    int kb = kt * 64 + lg * 16;
    s16x8 a_hi[2], a_lo[2];
#pragma unroll
    for (int mt = 0; mt < 2; ++mt) {
      int row = mt * 16 + l15;
      int off = (row * 512 + kb) ^ ((row & 7) << 4);
      a_hi[mt] = *(const s16x8*)((const char*)A_hi + off);
      a_lo[mt] = *(const s16x8*)((const char*)A_lo + off);
    }
    s16x8 b_hi[2], b_lo[2];
#pragma unroll
    for (int ntl = 0; ntl < 2; ++ntl) {
      int j = (w * 2 + ntl) * 16 + l15;
      size_t woff = (size_t)j * 256 + kt * 32 + lg * 8;
      b_hi[ntl] = *(const s16x8*)(whi + woff);
      b_lo[ntl] = *(const s16x8*)(wlo + woff);
    }
#pragma unroll
    for (int mt = 0; mt < 2; ++mt)
#pragma unroll
      for (int ntl = 0; ntl < 2; ++ntl) {
        acc[mt][ntl] = MFMA16(a_hi[mt], b_hi[ntl], acc[mt][ntl]);
        acc[mt][ntl] = MFMA16(a_hi[mt], b_lo[ntl], acc[mt][ntl]);
        acc[mt][ntl] = MFMA16(a_lo[mt], b_hi[ntl], acc[mt][ntl]);
      }
  }

  __syncthreads();  // done reading A; reuse as y tile

  float* ylds = (float*)A_hi;
#pragma unroll
  for (int mt = 0; mt < 2; ++mt)
#pragma unroll
    for (int ntl = 0; ntl < 2; ++ntl) {
      int col = (w * 2 + ntl) * 16 + l15;
#pragma unroll
      for (int r = 0; r < 4; ++r) {
        int row = mt * 16 + lg * 4 + r;
        float a = acc[mt][ntl][r] + bias[ntl];
        float yv = (a >= 0.f) ? a : NEG_SLOPE_C * a;
        int off = (row * 512 + col * 4) ^ ((row & 7) << 4);
        *(float*)((char*)ylds + off) = yv;
      }
    }
  __syncthreads();

#pragma unroll
  for (int i = 0; i < 4; ++i) {
    int f = i * 256 + t;
    int row = f >> 5;
    int c4 = f & 31;
    int off = (row * 512 + c4 * 16) ^ ((row & 7) << 4);
    float4 y = *(float4*)((char*)ylds + off);
    float ss = y.x * y.x + y.y * y.y + y.z * y.z + y.w * y.w;
#pragma unroll
    for (int m = 1; m <= 16; m <<= 1) ss += __shfl_xor(ss, m);
    float scale = 1.0f / fmaxf(sqrtf(ss), EPS_C);
    size_t g = (size_t)(nb + row) * 32 + c4;
    float yy[4] = {y.x, y.y, y.z, y.w};
    ushort4 h;
    unsigned short* hp = (unsigned short*)&h;
#pragma unroll
    for (int jj = 0; jj < 4; ++jj) hp[jj] = f2bf(yy[jj]);
    reinterpret_cast<ushort4*>(ego)[g] = h;
    float4 o = reinterpret_cast<float4*>(out)[g];
    o.x += y.x * scale;
    o.y += y.y * scale;
    o.z += y.z * scale;
    o.w += y.w * scale;
    reinterpret_cast<float4*>(out)[g] = o;
  }
}

// ---------------------------------------------------------------- launch
extern "C" void kernel_launch(void* const* d_in, const int* in_sizes, int n_in,
                              void* d_out, int out_size, void* d_ws,
                              size_t ws_size, hipStream_t stream) {
  const int* erow = (const int*)d_in[0];
  const int* ecol = (const int*)d_in[1];
  const float* eval = (const float*)d_in[2];
  const float* o_emb = (const float*)d_in[3];
  const int* u_id = (const int*)d_in[4];
  const float* user_emb = (const float*)d_in[5];
  const float* fc1_w = (const float*)d_in[6];
  const float* fc1_b = (const float*)d_in[7];
  const float* fc2_w = (const float*)d_in[8];
  const float* fc2_b = (const float*)d_in[9];
  float* out = (float*)d_out;
  int nnz = in_sizes[0];

  char* ws = (char*)d_ws;
  size_t off = 0;
  auto alloc = [&](size_t bytes) {
    void* p = ws + off;
    off += (bytes + 255) & ~(size_t)255;
    return p;
  };
  unsigned short* ego = (unsigned short*)alloc((size_t)N_NODES_C * EMBED_C * 2);
  // union region: cstage (54.1 MB, dead after refine) / side (102.4 MB)
  char* unionAB = (char*)alloc((size_t)N_NODES_C * EMBED_C * 4);
  int2* cstage = (int2*)unionAB;
  float* side = (float*)unionAB;
  int2* fstage = (int2*)alloc((size_t)NFINE * FCAP * 8);
  int* cgcur = (int*)alloc(NCOARSE * 4);
  int* fgcur = (int*)alloc(NFINE * 4);
  unsigned short* whi = (unsigned short*)alloc((size_t)LAYERS_C * 128 * 256 * 2);
  unsigned short* wlo = (unsigned short*)alloc((size_t)LAYERS_C * 128 * 256 * 2);

  init_gcur<<<(NFINE + 255) / 256, 256, 0, stream>>>(cgcur, fgcur);
  init_ego_out<<<(N_NODES_C * 32 + 255) / 256, 256, 0, stream>>>(
      user_emb, u_id, o_emb, ego, out);
  partition_edges<<<nnz / 2048, 256, 0, stream>>>(erow, ecol, eval, cgcur,
                                                  cstage, nnz);
  refine_buckets<<<NCOARSE * 32, 256, 0, stream>>>(cstage, cgcur, fgcur,
                                                   fstage);
  prep_w<<<(LAYERS_C * 128 * 256 + 255) / 256, 256, 0, stream>>>(fc1_w, fc2_w,
                                                                 whi, wlo);
  for (int l = 0; l < LAYERS_C; ++l) {
    spmm_bucket<<<NFB_USED, 512, 0, stream>>>(fstage, fgcur,
                                              (const unsigned*)ego, side);
    dense_mfma<<<N_NODES_C / 32, 256, 0, stream>>>(
        side, ego, whi + (size_t)l * 32768, wlo + (size_t)l * 32768,
        fc1_b + l * EMBED_C, fc2_b + l * EMBED_C, out);
  }
}